// Round 5
// baseline (588.523 us; speedup 1.0000x reference)
//
#include <hip/hip_runtime.h>

#define N_NODES  100000
#define N_EDGES  1600000
#define NODE_DIM 64
#define HID      32
#define NUM_LAYERS 3
#define SCAN_B   1024   // elements per scan1 block

// model kernels: 8 lanes per node; lane r owns channels 4r..4r+3 (float4).
// 256-thread block = 32 nodes; wave64 = 8 nodes.
#define NPB4  32
#define GRID4 (N_NODES / NPB4)   // 3125, exact

// ------------------------------- sort: CSR by dst ---------------------------
__global__ void zero_int_kernel(int* __restrict__ p, int n) {
    int i = blockIdx.x * blockDim.x + threadIdx.x;
    if (i < n) p[i] = 0;
}

__global__ void count_kernel(const int* __restrict__ ei, int* __restrict__ cnt) {
    int e = blockIdx.x * blockDim.x + threadIdx.x;
    if (e >= N_EDGES) return;
    atomicAdd(&cnt[ei[N_EDGES + e]], 1);
}

// scan1: per-block exclusive scan of cnt (1024 elems/block of 256 threads)
__global__ void scan1_kernel(const int* __restrict__ cnt, int* __restrict__ off,
                             int* __restrict__ bsum) {
    __shared__ int lds[256];
    int tid = threadIdx.x;
    int base = blockIdx.x * SCAN_B + tid * 4;
    int v0 = (base + 0 < N_NODES) ? cnt[base + 0] : 0;
    int v1 = (base + 1 < N_NODES) ? cnt[base + 1] : 0;
    int v2 = (base + 2 < N_NODES) ? cnt[base + 2] : 0;
    int v3 = (base + 3 < N_NODES) ? cnt[base + 3] : 0;
    int s1 = v0, s2 = v0 + v1, s3 = v0 + v1 + v2;
    int tsum = s3 + v3;
    lds[tid] = tsum;
    __syncthreads();
    for (int d = 1; d < 256; d <<= 1) {
        int t = lds[tid];
        int u = (tid >= d) ? lds[tid - d] : 0;
        __syncthreads();
        lds[tid] = t + u;
        __syncthreads();
    }
    int excl = lds[tid] - tsum;
    if (base + 0 < N_NODES) off[base + 0] = excl;
    if (base + 1 < N_NODES) off[base + 1] = excl + s1;
    if (base + 2 < N_NODES) off[base + 2] = excl + s2;
    if (base + 3 < N_NODES) off[base + 3] = excl + s3;
    if (tid == 255) bsum[blockIdx.x] = lds[255];
}

__global__ void scan2_kernel(const int* __restrict__ bsum, int* __restrict__ boff, int nb) {
    __shared__ int lds[256];
    int tid = threadIdx.x;
    int v = (tid < nb) ? bsum[tid] : 0;
    lds[tid] = v;
    __syncthreads();
    for (int d = 1; d < 256; d <<= 1) {
        int t = lds[tid];
        int u = (tid >= d) ? lds[tid - d] : 0;
        __syncthreads();
        lds[tid] = t + u;
        __syncthreads();
    }
    if (tid < nb) boff[tid] = lds[tid] - v;
}

// scan3: finalize off and write the mutable copy used by the atomic scatter
__global__ void scan3_kernel(int* __restrict__ off, int* __restrict__ posm,
                             const int* __restrict__ boff) {
    int i = blockIdx.x * blockDim.x + threadIdx.x;
    if (i < N_NODES) {
        int v = off[i] + boff[i / SCAN_B];
        off[i] = v;
        posm[i] = v;
    }
}

// scatter: atomic slot claim (order within a segment is irrelevant for a sum),
// ONE packed 8B store per edge.
__global__ void scatter_kernel(const int* __restrict__ ei,
                               const float* __restrict__ pos,
                               int* __restrict__ posm,
                               int2* __restrict__ recs) {
    int e = blockIdx.x * blockDim.x + threadIdx.x;
    if (e >= N_EDGES) return;
    int s = ei[e];
    int d = ei[N_EDGES + e];
    float dx = pos[d * 3 + 0] - pos[s * 3 + 0];
    float dy = pos[d * 3 + 1] - pos[s * 3 + 1];
    float dz = pos[d * 3 + 2] - pos[s * 3 + 2];
    int t = atomicAdd(&posm[d], 1);
    recs[t] = make_int2(s, __float_as_int(sqrtf(dx * dx + dy * dy + dz * dz)));
}

// ------------------------------- model helpers ------------------------------
__device__ __forceinline__ void fma4(float4& acc, float a, const float4 w) {
    acc.x = fmaf(a, w.x, acc.x);
    acc.y = fmaf(a, w.y, acc.y);
    acc.z = fmaf(a, w.z, acc.z);
    acc.w = fmaf(a, w.w, acc.w);
}

// acc += v @ W, W is 32x32 row-major, v distributed over an 8-lane group
// (lane r holds channels 4r..4r+3). Each lane produces its own 4 outputs.
__device__ __forceinline__ void matvec32(float4 v, const float* __restrict__ w,
                                         int r, float4& acc) {
    const float4* w4 = reinterpret_cast<const float4*>(w);
#pragma unroll
    for (int kk = 0; kk < 8; ++kk) {
        float a0 = __shfl(v.x, kk, 8);
        float a1 = __shfl(v.y, kk, 8);
        float a2 = __shfl(v.z, kk, 8);
        float a3 = __shfl(v.w, kk, 8);
        fma4(acc, a0, w4[(4 * kk + 0) * 8 + r]);
        fma4(acc, a1, w4[(4 * kk + 1) * 8 + r]);
        fma4(acc, a2, w4[(4 * kk + 2) * 8 + r]);
        fma4(acc, a3, w4[(4 * kk + 3) * 8 + r]);
    }
}

__device__ __forceinline__ float4 relu4(float4 v) {
    v.x = fmaxf(v.x, 0.0f); v.y = fmaxf(v.y, 0.0f);
    v.z = fmaxf(v.z, 0.0f); v.w = fmaxf(v.w, 0.0f);
    return v;
}

// ------------------------------- model kernels ------------------------------
__global__ void encoder_kernel(const float* __restrict__ feat,
                               const float* __restrict__ w1, const float* __restrict__ b1,
                               const float* __restrict__ w2, const float* __restrict__ b2,
                               float* __restrict__ xout) {
    int r = threadIdx.x & 7;
    int n = blockIdx.x * NPB4 + (threadIdx.x >> 3);
    const float4* f4 = reinterpret_cast<const float4*>(feat);
    float4 f0 = f4[(size_t)n * 16 + r];        // channels 4r..4r+3
    float4 f1 = f4[(size_t)n * 16 + 8 + r];    // channels 32+4r..32+4r+3
    float4 h = reinterpret_cast<const float4*>(b1)[r];
    matvec32(f0, w1, r, h);
    matvec32(f1, w1 + 32 * HID, r, h);
    h = relu4(h);
    float4 y = reinterpret_cast<const float4*>(b2)[r];
    matvec32(h, w2, r, y);
    reinterpret_cast<float4*>(xout)[(size_t)n * 8 + r] = y;
}

// per-layer node projections: p = x @ W1[0:32] + b1 (dst half), q = x @ W1[32:64] (src half)
__global__ void proj_kernel(const float* __restrict__ x,
                            const float* __restrict__ w1, const float* __restrict__ b1,
                            float* __restrict__ p, float* __restrict__ q) {
    int r = threadIdx.x & 7;
    int n = blockIdx.x * NPB4 + (threadIdx.x >> 3);
    float4 xv = reinterpret_cast<const float4*>(x)[(size_t)n * 8 + r];
    float4 pp = reinterpret_cast<const float4*>(b1)[r];
    float4 qq = make_float4(0.f, 0.f, 0.f, 0.f);
    matvec32(xv, w1, r, pp);
    matvec32(xv, w1 + HID * HID, r, qq);
    reinterpret_cast<float4*>(p)[(size_t)n * 8 + r] = pp;
    reinterpret_cast<float4*>(q)[(size_t)n * 8 + r] = qq;
}

// fused: CSR gather + relu-accum + (@W2 + deg*b2) + update MLP (+ optional output head)
__global__ void gather_update_kernel(float* __restrict__ x,
                                     const float* __restrict__ p,
                                     const float* __restrict__ q,
                                     const int2* __restrict__ recs,
                                     const int* __restrict__ off,
                                     const float* __restrict__ w1,   // for dist row (row 64)
                                     const float* __restrict__ w2,
                                     const float* __restrict__ b2,
                                     const float* __restrict__ uw1, const float* __restrict__ ub1,
                                     const float* __restrict__ uw2, const float* __restrict__ ub2,
                                     const float* __restrict__ ow,  const float* __restrict__ ob,
                                     float* __restrict__ fo) {
    int r = threadIdx.x & 7;
    int n = blockIdx.x * NPB4 + (threadIdx.x >> 3);
    int t0 = off[n];
    int t1 = (n == N_NODES - 1) ? N_EDGES : off[n + 1];

    const float4* q4 = reinterpret_cast<const float4*>(q);
    float4 pp = reinterpret_cast<const float4*>(p)[(size_t)n * 8 + r];
    float4 wd = reinterpret_cast<const float4*>(w1 + 2 * HID * HID)[r];  // dist row
    float4 rsum = make_float4(0.f, 0.f, 0.f, 0.f);

    // recs entries anywhere in [0,E) are valid (node id, dist) pairs, so
    // out-of-segment prefetch reads are safe; they're masked by k<m below.
    int pidx = t0 + r; if (pidx > N_EDGES - 1) pidx = N_EDGES - 1;
    int2 rec = recs[pidx];

    for (int t = t0; t < t1; t += 8) {
        // prefetch next chunk's records (unconditional, clamped)
        int nidx = t + 8 + r; if (nidx > N_EDGES - 1) nidx = N_EDGES - 1;
        int2 rec_next = recs[nidx];

        int m = t1 - t; if (m > 8) m = 8;   // uniform within the 8-lane group

        // phase A: issue all 8 q-row loads (keep them in flight together)
        float4 qv[8];
#pragma unroll
        for (int k = 0; k < 8; ++k) {
            int s = __shfl(rec.x, k, 8);
            qv[k] = q4[(size_t)s * 8 + r];
        }
        // phase B: consume
#pragma unroll
        for (int k = 0; k < 8; ++k) {
            float dt = __int_as_float(__shfl(rec.y, k, 8));
            float4 v = qv[k];
            float c0 = fmaxf(fmaf(dt, wd.x, pp.x + v.x), 0.0f);
            float c1 = fmaxf(fmaf(dt, wd.y, pp.y + v.y), 0.0f);
            float c2 = fmaxf(fmaf(dt, wd.z, pp.z + v.z), 0.0f);
            float c3 = fmaxf(fmaf(dt, wd.w, pp.w + v.w), 0.0f);
            bool ok = (k < m);
            rsum.x += ok ? c0 : 0.0f;
            rsum.y += ok ? c1 : 0.0f;
            rsum.z += ok ? c2 : 0.0f;
            rsum.w += ok ? c3 : 0.0f;
        }
        rec = rec_next;
    }

    // agg = rsum @ W2 + deg * b2
    float deg = (float)(t1 - t0);
    float4 agg = reinterpret_cast<const float4*>(b2)[r];
    agg.x *= deg; agg.y *= deg; agg.z *= deg; agg.w *= deg;
    matvec32(rsum, w2, r, agg);

    // update MLP: h = relu([x, agg] @ uw1 + ub1); y = h @ uw2 + ub2
    float4 xv = reinterpret_cast<const float4*>(x)[(size_t)n * 8 + r];
    float4 h = reinterpret_cast<const float4*>(ub1)[r];
    matvec32(xv, uw1, r, h);
    matvec32(agg, uw1 + HID * HID, r, h);
    h = relu4(h);
    float4 y = reinterpret_cast<const float4*>(ub2)[r];
    matvec32(h, uw2, r, y);

    if (fo != nullptr) {
        // final layer: fuse output head, write to out
        float4 z = reinterpret_cast<const float4*>(ob)[r];
        matvec32(y, ow, r, z);
        reinterpret_cast<float4*>(fo)[(size_t)n * 8 + r] = z;
    } else {
        reinterpret_cast<float4*>(x)[(size_t)n * 8 + r] = y;
    }
}

// ---------------------------------------------------------------------------
extern "C" void kernel_launch(void* const* d_in, const int* in_sizes, int n_in,
                              void* d_out, int out_size, void* d_ws, size_t ws_size,
                              hipStream_t stream) {
    const float* node_feat = (const float*)d_in[0];
    const float* pos       = (const float*)d_in[1];
    const int*   ei        = (const int*)  d_in[2];   // int32 on device
    const float* enc_w1    = (const float*)d_in[3];
    const float* enc_b1    = (const float*)d_in[4];
    const float* enc_w2    = (const float*)d_in[5];
    const float* enc_b2    = (const float*)d_in[6];
    const float* msg_w1    = (const float*)d_in[7];   // [3, 65, 32]
    const float* msg_b1    = (const float*)d_in[8];
    const float* msg_w2    = (const float*)d_in[9];   // [3, 32, 32]
    const float* msg_b2    = (const float*)d_in[10];
    const float* upd_w1    = (const float*)d_in[11];  // [3, 64, 32]
    const float* upd_b1    = (const float*)d_in[12];
    const float* upd_w2    = (const float*)d_in[13];
    const float* upd_b2    = (const float*)d_in[14];
    const float* out_w     = (const float*)d_in[15];
    const float* out_b     = (const float*)d_in[16];
    float* out = (float*)d_out;

    // workspace layout (4-byte elements), ~52 MB total
    char* ws = (char*)d_ws;
    float* x      = (float*)ws;                                   // N*32
    float* p      = x + (size_t)N_NODES * HID;                    // N*32
    float* q      = p + (size_t)N_NODES * HID;                    // N*32
    int2*  recs   = (int2*)(q + (size_t)N_NODES * HID);           // E (8B each)
    int*   posm   = (int*)(recs + (size_t)N_EDGES);               // N
    int*   cnt    = posm + N_NODES;                               // N
    int*   off    = cnt + N_NODES;                                // N+1 (off[N] unused)
    int*   bsum   = off + (N_NODES + 1);                          // <=256
    int*   boff   = bsum + 256;                                   // <=256

    const int B = 256;
    const int gridE = (N_EDGES + B - 1) / B;
    const int NB = (N_NODES + SCAN_B - 1) / SCAN_B;               // 98

    // ---- build CSR (once per launch) ----
    zero_int_kernel<<<(N_NODES + B - 1) / B, B, 0, stream>>>(cnt, N_NODES);
    count_kernel<<<gridE, B, 0, stream>>>(ei, cnt);
    scan1_kernel<<<NB, 256, 0, stream>>>(cnt, off, bsum);
    scan2_kernel<<<1, 256, 0, stream>>>(bsum, boff, NB);
    scan3_kernel<<<(N_NODES + B - 1) / B, B, 0, stream>>>(off, posm, boff);
    scatter_kernel<<<gridE, B, 0, stream>>>(ei, pos, posm, recs);

    // ---- model (8 lanes per node; 32 nodes per block) ----
    encoder_kernel<<<GRID4, B, 0, stream>>>(node_feat, enc_w1, enc_b1, enc_w2, enc_b2, x);

    for (int l = 0; l < NUM_LAYERS; ++l) {
        const float* w1 = msg_w1 + (size_t)l * (2 * HID + 1) * HID;
        bool last = (l == NUM_LAYERS - 1);
        proj_kernel<<<GRID4, B, 0, stream>>>(x, w1, msg_b1 + (size_t)l * HID, p, q);
        gather_update_kernel<<<GRID4, B, 0, stream>>>(
            x, p, q, recs, off,
            w1,
            msg_w2 + (size_t)l * HID * HID,
            msg_b2 + (size_t)l * HID,
            upd_w1 + (size_t)l * (2 * HID) * HID,
            upd_b1 + (size_t)l * HID,
            upd_w2 + (size_t)l * HID * HID,
            upd_b2 + (size_t)l * HID,
            last ? out_w : nullptr,
            last ? out_b : nullptr,
            last ? out : nullptr);
    }
}